// Round 2
// baseline (883.101 us; speedup 1.0000x reference)
//
#include <hip/hip_runtime.h>

#define B 8
#define C 19
#define H 512
#define W 512
#define P (H*W)          // 262144 pixels per plane
#define NPL 16           // 8 student planes + 8 teacher planes
#define BIGF 1e30f
#define NT 512           // threads per skel block

// ---------------------------------------------------------------------------
// prep: student softmax prob for class ci + teacher clip. Planes 0..7 =
// student (per batch), 8..15 = teacher. prob stays pristine (reduction input).
// ---------------------------------------------------------------------------
__global__ __launch_bounds__(256) void prep_kernel(
    const float* __restrict__ logits, const float* __restrict__ mask,
    const int* __restrict__ cls, float* __restrict__ prob)
{
    int tid = blockIdx.x * 256 + threadIdx.x;     // one thread = 4 pixels
    const int tot = B * (P / 4);
    if (tid >= tot) return;
    int b  = tid / (P / 4);
    int i4 = tid % (P / 4);
    int ci = *cls;

    const float4* lg = reinterpret_cast<const float4*>(logits) + (size_t)b * C * (P / 4) + i4;
    float4 v[C];
    float4 vc = make_float4(0.f, 0.f, 0.f, 0.f);
    #pragma unroll
    for (int c = 0; c < C; ++c) {
        float4 t = lg[(size_t)c * (P / 4)];
        v[c] = t;
        if (c == ci) vc = t;          // static indexing; predicated capture
    }
    float4 mx = v[0];
    #pragma unroll
    for (int c = 1; c < C; ++c) {
        mx.x = fmaxf(mx.x, v[c].x); mx.y = fmaxf(mx.y, v[c].y);
        mx.z = fmaxf(mx.z, v[c].z); mx.w = fmaxf(mx.w, v[c].w);
    }
    float4 s = make_float4(0.f, 0.f, 0.f, 0.f);
    #pragma unroll
    for (int c = 0; c < C; ++c) {
        s.x += expf(v[c].x - mx.x); s.y += expf(v[c].y - mx.y);
        s.z += expf(v[c].z - mx.z); s.w += expf(v[c].w - mx.w);
    }
    float4 p;
    p.x = expf(vc.x - mx.x) / s.x;
    p.y = expf(vc.y - mx.y) / s.y;
    p.z = expf(vc.z - mx.z) / s.z;
    p.w = expf(vc.w - mx.w) / s.w;

    float4* pr = reinterpret_cast<float4*>(prob);
    pr[(size_t)b * (P / 4) + i4] = p;

    float4 tm = reinterpret_cast<const float4*>(mask)[(size_t)b * (P / 4) + i4];
    tm.x = fminf(fmaxf(tm.x, 0.f), 1.f);
    tm.y = fminf(fmaxf(tm.y, 0.f), 1.f);
    tm.z = fminf(fmaxf(tm.z, 0.f), 1.f);
    tm.w = fminf(fmaxf(tm.w, 0.f), 1.f);
    pr[(size_t)(8 + b) * (P / 4) + i4] = tm;
}

// ---------------------------------------------------------------------------
// 3x3 erode (min) src->dst over staged region [K, 79-K]^2.
// Staged buffer uses replicate-clamped halo: erosion chains computed with
// clamped windows equal the jax +inf-padded semantics for all in-grid pixels
// (OOB-row values are upper bounds of in-window members; min unaffected).
// ---------------------------------------------------------------------------
template<int K>
__device__ __forceinline__ void erode3(const float (*__restrict__ s)[84],
                                       float (*__restrict__ d)[84])
{
    constexpr int R = 80 - 2 * K;
    for (int idx = threadIdx.x; idx < R * R; idx += NT) {
        int r = idx / R + K, c = idx % R + K;
        float m =    s[r-1][c-1];
        m = fminf(m, s[r-1][c  ]);
        m = fminf(m, s[r-1][c+1]);
        m = fminf(m, s[r  ][c-1]);
        m = fminf(m, s[r  ][c  ]);
        m = fminf(m, s[r  ][c+1]);
        m = fminf(m, s[r+1][c-1]);
        m = fminf(m, s[r+1][c  ]);
        m = fminf(m, s[r+1][c+1]);
        d[r][c] = m;
    }
}

// ---------------------------------------------------------------------------
// delta + sk update, sk in registers (8 px/thread over the 64x64 output).
// delta = relu(cur - dilate3_masked(nw)); sk += relu(delta - sk*delta).
// Dilation must IGNORE out-of-image neighbors (jax pads -inf): per-neighbor
// validity selects. CAP captures cur center (the im handoff value e^6).
// ---------------------------------------------------------------------------
template<bool CAP>
__device__ __forceinline__ void dstage(const float (*__restrict__ cur)[84],
                                       const float (*__restrict__ nw)[84],
                                       float* skr, float* cap, int ty0, int tx0)
{
    #pragma unroll
    for (int i = 0; i < 8; ++i) {
        int p  = i * NT + threadIdx.x;          // 0..4095
        int py = p >> 6, px = p & 63;
        int ly = py + 8, lx = px + 8;
        int gy = ty0 + py, gx = tx0 + px;
        bool r0 = gy > 0, r2 = gy < H - 1, c0 = gx > 0, c2 = gx < W - 1;
        float n00 = nw[ly-1][lx-1], n01 = nw[ly-1][lx], n02 = nw[ly-1][lx+1];
        float n10 = nw[ly  ][lx-1], n11 = nw[ly  ][lx], n12 = nw[ly  ][lx+1];
        float n20 = nw[ly+1][lx-1], n21 = nw[ly+1][lx], n22 = nw[ly+1][lx+1];
        float d = n11;
        d = fmaxf(d, r0        ? n01 : -BIGF);
        d = fmaxf(d, r2        ? n21 : -BIGF);
        d = fmaxf(d, c0        ? n10 : -BIGF);
        d = fmaxf(d, c2        ? n12 : -BIGF);
        d = fmaxf(d, (r0 && c0) ? n00 : -BIGF);
        d = fmaxf(d, (r0 && c2) ? n02 : -BIGF);
        d = fmaxf(d, (r2 && c0) ? n20 : -BIGF);
        d = fmaxf(d, (r2 && c2) ? n22 : -BIGF);
        float cc = cur[ly][lx];
        if (CAP) cap[i] = cc;
        float delta = fmaxf(cc - d, 0.f);
        float sv = skr[i];
        skr[i] = sv + fmaxf(delta - sv * delta, 0.f);
    }
}

// ---------------------------------------------------------------------------
// fused skeleton: 6 loop iterations per launch, sk in registers.
// MODE 0: first (includes init delta0, sk starts at 0, no gsk read)
// MODE 1: mid   (reads+writes gsk, writes im_out)
// MODE 2: last  (reads gsk; fused reduction via fp64 atomics; no writes)
// Halo radius 8 = m+2 (6 body iters need e^7 at radius 1). 80x80 staged.
// ---------------------------------------------------------------------------
template<int MODE>
__global__ __launch_bounds__(NT) void skel_kernel(
    const float* __restrict__ in, float* __restrict__ im_out,
    float* __restrict__ gsk, const float* __restrict__ prob,
    double* __restrict__ sums)
{
    __shared__ float bufA[80][84];
    __shared__ float bufB[80][84];
    const int pl  = blockIdx.z;
    const int ty0 = blockIdx.y * 64, tx0 = blockIdx.x * 64;
    const float* ip = in + (size_t)pl * P;

    for (int idx = threadIdx.x; idx < 80 * 80; idx += NT) {
        int ly = idx / 80, lx = idx % 80;
        int gy = min(max(ty0 - 8 + ly, 0), H - 1);
        int gx = min(max(tx0 - 8 + lx, 0), W - 1);
        bufA[ly][lx] = ip[gy * W + gx];
    }
    float skr[8], cap[8];
    if (MODE == 0) {
        #pragma unroll
        for (int i = 0; i < 8; ++i) skr[i] = 0.f;
    } else {
        #pragma unroll
        for (int i = 0; i < 8; ++i) {
            int p = i * NT + threadIdx.x;
            skr[i] = gsk[(size_t)pl * P + (size_t)(ty0 + (p >> 6)) * W + tx0 + (p & 63)];
        }
    }
    __syncthreads();
    erode3<1>(bufA, bufB); __syncthreads();                      // B = e^1
    if (MODE == 0) { dstage<false>(bufA, bufB, skr, cap, ty0, tx0); __syncthreads(); } // delta0
    erode3<2>(bufB, bufA); __syncthreads();                      // A = e^2
    dstage<false>(bufB, bufA, skr, cap, ty0, tx0); __syncthreads();
    erode3<3>(bufA, bufB); __syncthreads();                      // B = e^3
    dstage<false>(bufA, bufB, skr, cap, ty0, tx0); __syncthreads();
    erode3<4>(bufB, bufA); __syncthreads();                      // A = e^4
    dstage<false>(bufB, bufA, skr, cap, ty0, tx0); __syncthreads();
    erode3<5>(bufA, bufB); __syncthreads();                      // B = e^5
    dstage<false>(bufA, bufB, skr, cap, ty0, tx0); __syncthreads();
    erode3<6>(bufB, bufA); __syncthreads();                      // A = e^6
    dstage<false>(bufB, bufA, skr, cap, ty0, tx0); __syncthreads();
    erode3<7>(bufA, bufB); __syncthreads();                      // B = e^7
    dstage<true>(bufA, bufB, skr, cap, ty0, tx0);                // delta6, cap = e^6

    if (MODE < 2) {
        #pragma unroll
        for (int i = 0; i < 8; ++i) {
            int p = i * NT + threadIdx.x;
            size_t gi = (size_t)pl * P + (size_t)(ty0 + (p >> 6)) * W + tx0 + (p & 63);
            im_out[gi] = cap[i];
            gsk[gi]    = skr[i];
        }
    } else {
        // fused reduction: student plane -> sums[b][0,1]; teacher -> [2,3]
        const float* op = prob + (size_t)(pl ^ 8) * P;
        float a0 = 0.f, a1 = 0.f;
        #pragma unroll
        for (int i = 0; i < 8; ++i) {
            int p = i * NT + threadIdx.x;
            float o = op[(size_t)(ty0 + (p >> 6)) * W + tx0 + (p & 63)];
            a0 += skr[i] * o;
            a1 += skr[i];
        }
        #pragma unroll
        for (int off = 32; off > 0; off >>= 1) {
            a0 += __shfl_down(a0, off);
            a1 += __shfl_down(a1, off);
        }
        __syncthreads();                     // bufA reuse as scratch
        float* scratch = &bufA[0][0];
        int wv = threadIdx.x >> 6, ln = threadIdx.x & 63;
        if (ln == 0) { scratch[wv * 2] = a0; scratch[wv * 2 + 1] = a1; }
        __syncthreads();
        if (threadIdx.x == 0) {
            double s0 = 0.0, s1 = 0.0;
            for (int wvi = 0; wvi < NT / 64; ++wvi) {
                s0 += (double)scratch[wvi * 2];
                s1 += (double)scratch[wvi * 2 + 1];
            }
            int b = pl & 7, base = (pl < 8) ? 0 : 2;
            atomicAdd(&sums[b * 4 + base + 0], s0);
            atomicAdd(&sums[b * 4 + base + 1], s1);
        }
    }
}

__global__ void zero_sums_kernel(double* __restrict__ sums)
{
    if (threadIdx.x < 32) sums[threadIdx.x] = 0.0;
}

__global__ void final_kernel(const double* __restrict__ sums, float* __restrict__ out)
{
    if (threadIdx.x == 0) {
        double acc = 0.0;
        for (int b = 0; b < 8; ++b) {
            double tprec = (sums[b * 4 + 0] + 1e-6) / (sums[b * 4 + 1] + 1e-6);
            double tsens = (sums[b * 4 + 2] + 1e-6) / (sums[b * 4 + 3] + 1e-6);
            double cl    = (2.0 * tprec * tsens + 1e-6) / (tprec + tsens + 1e-6);
            acc += 1.0 - cl;
        }
        out[0] = (float)(acc / 8.0);
    }
}

extern "C" void kernel_launch(void* const* d_in, const int* in_sizes, int n_in,
                              void* d_out, int out_size, void* d_ws, size_t ws_size,
                              hipStream_t stream)
{
    const float* logits = (const float*)d_in[0];
    const float* mask   = (const float*)d_in[1];
    const int*   cls    = (const int*)d_in[2];
    float* out = (float*)d_out;

    float*  ws   = (float*)d_ws;
    float*  prob = ws;                          // 16 planes (pristine)
    float*  imA  = ws + (size_t)16 * P;
    float*  imB  = ws + (size_t)32 * P;
    float*  gsk  = ws + (size_t)48 * P;         // skeleton accumulator
    double* sums = (double*)(ws + (size_t)64 * P);  // 32 doubles

    dim3 sg(8, 8, NPL);
    zero_sums_kernel<<<1, 64, 0, stream>>>(sums);
    prep_kernel<<<(B * (P / 4) + 255) / 256, 256, 0, stream>>>(logits, mask, cls, prob);
    skel_kernel<0><<<sg, NT, 0, stream>>>(prob, imA, gsk, prob, sums);  // d0 + iters 1-6
    skel_kernel<1><<<sg, NT, 0, stream>>>(imA, imB, gsk, prob, sums);   // iters 7-12
    skel_kernel<1><<<sg, NT, 0, stream>>>(imB, imA, gsk, prob, sums);   // iters 13-18
    skel_kernel<2><<<sg, NT, 0, stream>>>(imA, nullptr, gsk, prob, sums); // 19-24 + reduce
    final_kernel<<<1, 64, 0, stream>>>(sums, out);
}

// Round 4
// 384.010 us; speedup vs baseline: 2.2997x; 2.2997x over previous
//
#include <hip/hip_runtime.h>

#define B 8
#define C 19
#define H 512
#define W 512
#define P (H*W)          // pixels per plane
#define NPL 16           // 8 student + 8 teacher planes
#define BIGF 1e30f
#define NT 512           // threads per skel block
#define HR 14            // halo radius (E+1)
#define SR 92            // staged rows = 64 + 2*HR
#define SC 96            // staged col window / stride (tx0-16 .. tx0+79)
#define E  13            // erode passes per launch

__device__ __forceinline__ float min3f(float a, float b, float c) { return fminf(fminf(a, b), c); }
__device__ __forceinline__ float max3f(float a, float b, float c) { return fmaxf(fmaxf(a, b), c); }

// ---------------------------------------------------------------------------
// prep: student softmax prob for class ci + teacher clip.
// ---------------------------------------------------------------------------
__global__ __launch_bounds__(256) void prep_kernel(
    const float* __restrict__ logits, const float* __restrict__ mask,
    const int* __restrict__ cls, float* __restrict__ prob)
{
    int tid = blockIdx.x * 256 + threadIdx.x;
    const int tot = B * (P / 4);
    if (tid >= tot) return;
    int b  = tid / (P / 4);
    int i4 = tid % (P / 4);
    int ci = *cls;

    const float4* lg = reinterpret_cast<const float4*>(logits) + (size_t)b * C * (P / 4) + i4;
    float4 v[C];
    float4 vc = make_float4(0.f, 0.f, 0.f, 0.f);
    #pragma unroll
    for (int c = 0; c < C; ++c) {
        float4 t = lg[(size_t)c * (P / 4)];
        v[c] = t;
        if (c == ci) vc = t;
    }
    float4 mx = v[0];
    #pragma unroll
    for (int c = 1; c < C; ++c) {
        mx.x = fmaxf(mx.x, v[c].x); mx.y = fmaxf(mx.y, v[c].y);
        mx.z = fmaxf(mx.z, v[c].z); mx.w = fmaxf(mx.w, v[c].w);
    }
    float4 s = make_float4(0.f, 0.f, 0.f, 0.f);
    #pragma unroll
    for (int c = 0; c < C; ++c) {
        s.x += expf(v[c].x - mx.x); s.y += expf(v[c].y - mx.y);
        s.z += expf(v[c].z - mx.z); s.w += expf(v[c].w - mx.w);
    }
    float4 p;
    p.x = expf(vc.x - mx.x) / s.x;
    p.y = expf(vc.y - mx.y) / s.y;
    p.z = expf(vc.z - mx.z) / s.z;
    p.w = expf(vc.w - mx.w) / s.w;

    float4* pr = reinterpret_cast<float4*>(prob);
    pr[(size_t)b * (P / 4) + i4] = p;

    float4 tm = reinterpret_cast<const float4*>(mask)[(size_t)b * (P / 4) + i4];
    tm.x = fminf(fmaxf(tm.x, 0.f), 1.f);
    tm.y = fminf(fmaxf(tm.y, 0.f), 1.f);
    tm.z = fminf(fmaxf(tm.z, 0.f), 1.f);
    tm.w = fminf(fmaxf(tm.w, 0.f), 1.f);
    pr[(size_t)(8 + b) * (P / 4) + i4] = tm;
}

// ---------------------------------------------------------------------------
// 3x3 erode pass p over staged tile (float4 groups, shfl edges).
// Valid region shrinks by 1/pass; fixed 24 groups/row (garbage cols proven
// never to feed valid outputs).
// ---------------------------------------------------------------------------
__device__ __forceinline__ void erode_pass(const float* __restrict__ src,
                                           float* __restrict__ dst, int p, int tid)
{
    const int r0 = p;
    const int n  = (SR - 2 * p) * 24;
    const int lane = tid & 63;
    for (int idx = tid; idx < n; idx += NT) {
        int r = r0 + idx / 24, g = idx % 24, c = 4 * g;
        const float* s1 = src + r * SC + c;
        float4 a  = *reinterpret_cast<const float4*>(s1 - SC);
        float4 b  = *reinterpret_cast<const float4*>(s1);
        float4 cc = *reinterpret_cast<const float4*>(s1 + SC);
        float4 vm;
        vm.x = min3f(a.x, b.x, cc.x);
        vm.y = min3f(a.y, b.y, cc.y);
        vm.z = min3f(a.z, b.z, cc.z);
        vm.w = min3f(a.w, b.w, cc.w);
        float vL = __shfl_up(vm.w, 1);
        float vR = __shfl_down(vm.x, 1);
        if (g == 0  || lane == 0)  vL = min3f(s1[-SC - 1], s1[-1], s1[SC - 1]);
        if (g == 23 || lane == 63) vR = min3f(s1[-SC + 4], s1[4], s1[SC + 4]);
        float4 o;
        o.x = min3f(vL,   vm.x, vm.y);
        o.y = min3f(vm.x, vm.y, vm.z);
        o.z = min3f(vm.y, vm.z, vm.w);
        o.w = min3f(vm.z, vm.w, vR);
        *reinterpret_cast<float4*>(dst + r * SC + c) = o;
    }
}

// ---------------------------------------------------------------------------
// masked 3x3 dilate of e-buffer at one output group (image-border -inf pad).
// ---------------------------------------------------------------------------
__device__ __forceinline__ float4 dilate4(const float* __restrict__ e,
                                          int lr, int lc, int gy, int gxb,
                                          bool fbL, bool fbR)
{
    const float* p0 = e + (lr - 1) * SC + lc;
    const float* p1 = e + lr * SC + lc;
    const float* p2 = e + (lr + 1) * SC + lc;
    float4 a = *reinterpret_cast<const float4*>(p0);
    float4 b = *reinterpret_cast<const float4*>(p1);
    float4 c = *reinterpret_cast<const float4*>(p2);
    const bool t = (gy > 0), u = (gy < H - 1);
    float4 vm;
    vm.x = fmaxf(b.x, fmaxf(t ? a.x : -BIGF, u ? c.x : -BIGF));
    vm.y = fmaxf(b.y, fmaxf(t ? a.y : -BIGF, u ? c.y : -BIGF));
    vm.z = fmaxf(b.z, fmaxf(t ? a.z : -BIGF, u ? c.z : -BIGF));
    vm.w = fmaxf(b.w, fmaxf(t ? a.w : -BIGF, u ? c.w : -BIGF));
    float vL = __shfl_up(vm.w, 1);
    float vR = __shfl_down(vm.x, 1);
    if (fbL) vL = max3f(t ? p0[-1] : -BIGF, p1[-1], u ? p2[-1] : -BIGF);
    if (fbR) vR = max3f(t ? p0[4]  : -BIGF, p1[4],  u ? p2[4]  : -BIGF);
    if (gxb == 0)     vL = -BIGF;
    if (gxb == W - 4) vR = -BIGF;
    float4 d;
    d.x = max3f(vL,   vm.x, vm.y);
    d.y = max3f(vm.x, vm.y, vm.z);
    d.z = max3f(vm.y, vm.z, vm.w);
    d.w = max3f(vm.z, vm.w, vR);
    return d;
}

// ---------------------------------------------------------------------------
// fused skeleton, 13 erode passes / launch, sk in registers, 1 sync/iter.
// MODE 0: first launch (delta0..delta12; writes im_out=e^12 and gsk)
// MODE 2: last  launch (delta13..delta24; fused reduction, no writes)
// ---------------------------------------------------------------------------
template<int MODE>
__global__ __launch_bounds__(NT, 4) void skel_kernel(
    const float* __restrict__ in, float* __restrict__ im_out,
    float* __restrict__ gsk, const float* __restrict__ prob,
    double* __restrict__ sums)
{
    __shared__ __align__(16) float lds[2 * SR * SC + 32];
    float* const bx = lds + 16;          // front guard 16 floats
    float* const by = bx + SR * SC;
    const int pl  = blockIdx.z;
    const int ty0 = blockIdx.y * 64, tx0 = blockIdx.x * 64;
    const int tid = threadIdx.x;
    const float* ip = in + (size_t)pl * P;
    const size_t gbase = (size_t)pl * P;

    // this thread's two output groups (4096 px / 512 thr = 2 float4 groups)
    const int jA  = tid & 15;                    // same for both groups
    const int pyA = tid >> 4, pyB = pyA + 32;
    const int lcA = 16 + 4 * jA;
    const int lrA = pyA + HR, lrB = pyB + HR;
    const int gyA = ty0 + pyA, gyB = ty0 + pyB;
    const int gxb = tx0 + 4 * jA;
    const bool fbL = (jA == 0)  || ((tid & 63) == 0);
    const bool fbR = (jA == 15) || ((tid & 63) == 63);

    // ---- stage e^0 into bx (replicate clamp; exact for erosion chains) ----
    const bool xin = (tx0 >= 16) && (tx0 <= W - 80);
    for (int idx = tid; idx < SR * 24; idx += NT) {
        int r = idx / 24, g = idx % 24;
        int gy = ty0 - HR + r; gy = min(max(gy, 0), H - 1);
        int gx0 = tx0 - 16 + 4 * g;
        float4 v;
        if (xin) {
            v = *reinterpret_cast<const float4*>(ip + (size_t)gy * W + gx0);
        } else {
            const float* rp = ip + (size_t)gy * W;
            v.x = rp[min(max(gx0,     0), W - 1)];
            v.y = rp[min(max(gx0 + 1, 0), W - 1)];
            v.z = rp[min(max(gx0 + 2, 0), W - 1)];
            v.w = rp[min(max(gx0 + 3, 0), W - 1)];
        }
        *reinterpret_cast<float4*>(&bx[r * SC + 4 * g]) = v;
    }

    float4 sk0, sk1;
    if (MODE == 0) {
        sk0 = make_float4(0.f, 0.f, 0.f, 0.f);
        sk1 = sk0;
    } else {
        sk0 = *reinterpret_cast<const float4*>(gsk + gbase + (size_t)gyA * W + gxb);
        sk1 = *reinterpret_cast<const float4*>(gsk + gbase + (size_t)gyB * W + gxb);
    }
    __syncthreads();

    // ---- phase 1: erode1 bx->by ; capture e^0 centers ----
    erode_pass(bx, by, 1, tid);
    float4 curA = *reinterpret_cast<const float4*>(bx + lrA * SC + lcA);
    float4 curB = *reinterpret_cast<const float4*>(bx + lrB * SC + lcA);
    __syncthreads();

    // ---- phases p=2..E : delta_{p-2} || capture e^{p-1} || erode_p ----
    for (int p = 2; p <= E; ++p) {
        const float* src = (p & 1) ? bx : by;    // holds e^{p-1}
        float*       dst = (p & 1) ? by : bx;
        if (MODE == 0 || p > 2) {
            float4 dA = dilate4(src, lrA, lcA, gyA, gxb, fbL, fbR);
            float4 dB = dilate4(src, lrB, lcA, gyB, gxb, fbL, fbR);
            float4 del;
            del.x = fmaxf(curA.x - dA.x, 0.f); del.y = fmaxf(curA.y - dA.y, 0.f);
            del.z = fmaxf(curA.z - dA.z, 0.f); del.w = fmaxf(curA.w - dA.w, 0.f);
            sk0.x += fmaxf(del.x - sk0.x * del.x, 0.f);
            sk0.y += fmaxf(del.y - sk0.y * del.y, 0.f);
            sk0.z += fmaxf(del.z - sk0.z * del.z, 0.f);
            sk0.w += fmaxf(del.w - sk0.w * del.w, 0.f);
            del.x = fmaxf(curB.x - dB.x, 0.f); del.y = fmaxf(curB.y - dB.y, 0.f);
            del.z = fmaxf(curB.z - dB.z, 0.f); del.w = fmaxf(curB.w - dB.w, 0.f);
            sk1.x += fmaxf(del.x - sk1.x * del.x, 0.f);
            sk1.y += fmaxf(del.y - sk1.y * del.y, 0.f);
            sk1.z += fmaxf(del.z - sk1.z * del.z, 0.f);
            sk1.w += fmaxf(del.w - sk1.w * del.w, 0.f);
        }
        float4 nxtA = *reinterpret_cast<const float4*>(src + lrA * SC + lcA);
        float4 nxtB = *reinterpret_cast<const float4*>(src + lrB * SC + lcA);
        erode_pass(src, dst, p, tid);
        __syncthreads();
        curA = nxtA; curB = nxtB;
    }

    // ---- final delta_{E-1}: cur = e^{E-1}, dilate e^E (in by, E odd) ----
    {
        float4 dA = dilate4(by, lrA, lcA, gyA, gxb, fbL, fbR);
        float4 dB = dilate4(by, lrB, lcA, gyB, gxb, fbL, fbR);
        float4 del;
        del.x = fmaxf(curA.x - dA.x, 0.f); del.y = fmaxf(curA.y - dA.y, 0.f);
        del.z = fmaxf(curA.z - dA.z, 0.f); del.w = fmaxf(curA.w - dA.w, 0.f);
        sk0.x += fmaxf(del.x - sk0.x * del.x, 0.f);
        sk0.y += fmaxf(del.y - sk0.y * del.y, 0.f);
        sk0.z += fmaxf(del.z - sk0.z * del.z, 0.f);
        sk0.w += fmaxf(del.w - sk0.w * del.w, 0.f);
        del.x = fmaxf(curB.x - dB.x, 0.f); del.y = fmaxf(curB.y - dB.y, 0.f);
        del.z = fmaxf(curB.z - dB.z, 0.f); del.w = fmaxf(curB.w - dB.w, 0.f);
        sk1.x += fmaxf(del.x - sk1.x * del.x, 0.f);
        sk1.y += fmaxf(del.y - sk1.y * del.y, 0.f);
        sk1.z += fmaxf(del.z - sk1.z * del.z, 0.f);
        sk1.w += fmaxf(del.w - sk1.w * del.w, 0.f);
    }

    if (MODE == 0) {
        // handoff: im = e^{E-1} (= curA/curB, still live), sk accumulator
        *reinterpret_cast<float4*>(im_out + gbase + (size_t)gyA * W + gxb) = curA;
        *reinterpret_cast<float4*>(im_out + gbase + (size_t)gyB * W + gxb) = curB;
        *reinterpret_cast<float4*>(gsk + gbase + (size_t)gyA * W + gxb) = sk0;
        *reinterpret_cast<float4*>(gsk + gbase + (size_t)gyB * W + gxb) = sk1;
    } else {
        // fused reduction: student plane -> sums[b][0,1]; teacher -> [2,3]
        const float* op = prob + (size_t)(pl ^ 8) * P;
        float4 tA = *reinterpret_cast<const float4*>(op + (size_t)gyA * W + gxb);
        float4 tB = *reinterpret_cast<const float4*>(op + (size_t)gyB * W + gxb);
        float a0 = sk0.x * tA.x + sk0.y * tA.y + sk0.z * tA.z + sk0.w * tA.w
                 + sk1.x * tB.x + sk1.y * tB.y + sk1.z * tB.z + sk1.w * tB.w;
        float a1 = sk0.x + sk0.y + sk0.z + sk0.w + sk1.x + sk1.y + sk1.z + sk1.w;
        #pragma unroll
        for (int off = 32; off > 0; off >>= 1) {
            a0 += __shfl_down(a0, off);
            a1 += __shfl_down(a1, off);
        }
        __syncthreads();
        float* scratch = lds;
        int wv = tid >> 6, ln = tid & 63;
        if (ln == 0) { scratch[wv * 2] = a0; scratch[wv * 2 + 1] = a1; }
        __syncthreads();
        if (tid == 0) {
            double s0 = 0.0, s1 = 0.0;
            for (int w = 0; w < NT / 64; ++w) {
                s0 += (double)scratch[w * 2];
                s1 += (double)scratch[w * 2 + 1];
            }
            int b = pl & 7, base = (pl < 8) ? 0 : 2;
            atomicAdd(&sums[b * 4 + base + 0], s0);
            atomicAdd(&sums[b * 4 + base + 1], s1);
        }
    }
}

__global__ void zero_sums_kernel(double* __restrict__ sums)
{
    if (threadIdx.x < 32) sums[threadIdx.x] = 0.0;
}

__global__ void final_kernel(const double* __restrict__ sums, float* __restrict__ out)
{
    if (threadIdx.x == 0) {
        double acc = 0.0;
        for (int b = 0; b < 8; ++b) {
            double tprec = (sums[b * 4 + 0] + 1e-6) / (sums[b * 4 + 1] + 1e-6);
            double tsens = (sums[b * 4 + 2] + 1e-6) / (sums[b * 4 + 3] + 1e-6);
            double cl    = (2.0 * tprec * tsens + 1e-6) / (tprec + tsens + 1e-6);
            acc += 1.0 - cl;
        }
        out[0] = (float)(acc / 8.0);
    }
}

extern "C" void kernel_launch(void* const* d_in, const int* in_sizes, int n_in,
                              void* d_out, int out_size, void* d_ws, size_t ws_size,
                              hipStream_t stream)
{
    const float* logits = (const float*)d_in[0];
    const float* mask   = (const float*)d_in[1];
    const int*   cls    = (const int*)d_in[2];
    float* out = (float*)d_out;

    float*  ws   = (float*)d_ws;
    float*  prob = ws;                          // 16 planes (pristine)
    float*  imA  = ws + (size_t)16 * P;         // e^12 handoff
    float*  gsk  = ws + (size_t)32 * P;         // skeleton accumulator
    double* sums = (double*)(ws + (size_t)48 * P);   // 32 doubles

    dim3 sg(8, 8, NPL);
    zero_sums_kernel<<<1, 64, 0, stream>>>(sums);
    prep_kernel<<<(B * (P / 4) + 255) / 256, 256, 0, stream>>>(logits, mask, cls, prob);
    skel_kernel<0><<<sg, NT, 0, stream>>>(prob, imA, gsk, prob, sums);    // d0..d12
    skel_kernel<2><<<sg, NT, 0, stream>>>(imA, nullptr, gsk, prob, sums); // d13..d24 + reduce
    final_kernel<<<1, 64, 0, stream>>>(sums, out);
}

// Round 6
// 363.981 us; speedup vs baseline: 2.4262x; 1.0550x over previous
//
#include <hip/hip_runtime.h>

#define B 8
#define C 19
#define H 512
#define W 512
#define P (H*W)          // pixels per plane
#define NPL 16           // 8 student + 8 teacher planes
#define BIGF 1e30f
#define NT 512           // threads per skel block
#define HR 14            // halo radius (E+1)
#define SR 92            // staged rows = 64 + 2*HR
#define SC 96            // staged col window / stride (tx0-16 .. tx0+79)
#define E  13            // erode passes per launch

__device__ __forceinline__ float min3f(float a, float b, float c) { return fminf(fminf(a, b), c); }
__device__ __forceinline__ float max3f(float a, float b, float c) { return fmaxf(fmaxf(a, b), c); }
__device__ __forceinline__ float4 ld4(const float* p) { return *reinterpret_cast<const float4*>(p); }

// ---------------------------------------------------------------------------
// prep: student softmax prob for class ci + teacher clip. Block 0 also zeros
// the sums accumulator (consumed 2 dispatches later by skel<2>).
// ---------------------------------------------------------------------------
__global__ __launch_bounds__(256) void prep_kernel(
    const float* __restrict__ logits, const float* __restrict__ mask,
    const int* __restrict__ cls, float* __restrict__ prob,
    double* __restrict__ sums)
{
    if (blockIdx.x == 0 && threadIdx.x < 32) sums[threadIdx.x] = 0.0;
    int tid = blockIdx.x * 256 + threadIdx.x;
    const int tot = B * (P / 4);
    if (tid >= tot) return;
    int b  = tid / (P / 4);
    int i4 = tid % (P / 4);
    int ci = *cls;

    const float4* lg = reinterpret_cast<const float4*>(logits) + (size_t)b * C * (P / 4) + i4;
    float4 v[C];
    float4 vc = make_float4(0.f, 0.f, 0.f, 0.f);
    #pragma unroll
    for (int c = 0; c < C; ++c) {
        float4 t = lg[(size_t)c * (P / 4)];
        v[c] = t;
        if (c == ci) vc = t;
    }
    float4 mx = v[0];
    #pragma unroll
    for (int c = 1; c < C; ++c) {
        mx.x = fmaxf(mx.x, v[c].x); mx.y = fmaxf(mx.y, v[c].y);
        mx.z = fmaxf(mx.z, v[c].z); mx.w = fmaxf(mx.w, v[c].w);
    }
    float4 s = make_float4(0.f, 0.f, 0.f, 0.f);
    #pragma unroll
    for (int c = 0; c < C; ++c) {
        s.x += expf(v[c].x - mx.x); s.y += expf(v[c].y - mx.y);
        s.z += expf(v[c].z - mx.z); s.w += expf(v[c].w - mx.w);
    }
    float4 p;
    p.x = expf(vc.x - mx.x) / s.x;
    p.y = expf(vc.y - mx.y) / s.y;
    p.z = expf(vc.z - mx.z) / s.z;
    p.w = expf(vc.w - mx.w) / s.w;

    float4* pr = reinterpret_cast<float4*>(prob);
    pr[(size_t)b * (P / 4) + i4] = p;

    float4 tm = reinterpret_cast<const float4*>(mask)[(size_t)b * (P / 4) + i4];
    tm.x = fminf(fmaxf(tm.x, 0.f), 1.f);
    tm.y = fminf(fmaxf(tm.y, 0.f), 1.f);
    tm.z = fminf(fmaxf(tm.z, 0.f), 1.f);
    tm.w = fminf(fmaxf(tm.w, 0.f), 1.f);
    pr[(size_t)(8 + b) * (P / 4) + i4] = tm;
}

// ---------------------------------------------------------------------------
// erode one float4 group at staged (r, col c). shfl edges; fL/fR force the
// scalar-column fallback (group-boundary / lane-boundary cases).
// ---------------------------------------------------------------------------
__device__ __forceinline__ float4 erode_grp(const float* __restrict__ src,
                                            int r, int c, bool fL, bool fR)
{
    const float* s1 = src + r * SC + c;
    float4 a = ld4(s1 - SC), b = ld4(s1), cc = ld4(s1 + SC);
    float4 vm;
    vm.x = min3f(a.x, b.x, cc.x);
    vm.y = min3f(a.y, b.y, cc.y);
    vm.z = min3f(a.z, b.z, cc.z);
    vm.w = min3f(a.w, b.w, cc.w);
    float vL = __shfl_up(vm.w, 1);
    float vR = __shfl_down(vm.x, 1);
    if (fL) vL = min3f(s1[-SC - 1], s1[-1], s1[SC - 1]);
    if (fR) vR = min3f(s1[-SC + 4], s1[4], s1[SC + 4]);
    float4 o;
    o.x = min3f(vL,   vm.x, vm.y);
    o.y = min3f(vm.x, vm.y, vm.z);
    o.z = min3f(vm.y, vm.z, vm.w);
    o.w = min3f(vm.z, vm.w, vR);
    return o;
}

// ---------------------------------------------------------------------------
// fused erode + capture-center + (optionally) masked dilate, all from ONE set
// of 3 b128 loads. Dilate masks image-border rows/cols (-inf pad semantics).
// ---------------------------------------------------------------------------
template<bool DODIL>
__device__ __forceinline__ float4 fused_grp(const float* __restrict__ src,
    int lr, int c, int gy, int gxb, bool fL, bool fR,
    float4* __restrict__ bcap, float4* __restrict__ dil)
{
    const float* s1 = src + lr * SC + c;
    float4 a = ld4(s1 - SC), b = ld4(s1), cc = ld4(s1 + SC);
    *bcap = b;
    float eL0 = 0.f, eL1 = 0.f, eL2 = 0.f, eR0 = 0.f, eR1 = 0.f, eR2 = 0.f;
    if (fL) { eL0 = s1[-SC - 1]; eL1 = s1[-1]; eL2 = s1[SC - 1]; }
    if (fR) { eR0 = s1[-SC + 4]; eR1 = s1[4];  eR2 = s1[SC + 4]; }
    float4 vm;
    vm.x = min3f(a.x, b.x, cc.x);
    vm.y = min3f(a.y, b.y, cc.y);
    vm.z = min3f(a.z, b.z, cc.z);
    vm.w = min3f(a.w, b.w, cc.w);
    float vL = __shfl_up(vm.w, 1);
    float vR = __shfl_down(vm.x, 1);
    if (fL) vL = min3f(eL0, eL1, eL2);
    if (fR) vR = min3f(eR0, eR1, eR2);
    float4 o;
    o.x = min3f(vL,   vm.x, vm.y);
    o.y = min3f(vm.x, vm.y, vm.z);
    o.z = min3f(vm.y, vm.z, vm.w);
    o.w = min3f(vm.z, vm.w, vR);
    if (DODIL) {
        const bool t = (gy > 0), u = (gy < H - 1);
        float4 xm;
        xm.x = fmaxf(b.x, fmaxf(t ? a.x : -BIGF, u ? cc.x : -BIGF));
        xm.y = fmaxf(b.y, fmaxf(t ? a.y : -BIGF, u ? cc.y : -BIGF));
        xm.z = fmaxf(b.z, fmaxf(t ? a.z : -BIGF, u ? cc.z : -BIGF));
        xm.w = fmaxf(b.w, fmaxf(t ? a.w : -BIGF, u ? cc.w : -BIGF));
        float xL = __shfl_up(xm.w, 1);
        float xR = __shfl_down(xm.x, 1);
        if (fL) xL = max3f(t ? eL0 : -BIGF, eL1, u ? eL2 : -BIGF);
        if (fR) xR = max3f(t ? eR0 : -BIGF, eR1, u ? eR2 : -BIGF);
        if (gxb == 0)     xL = -BIGF;
        if (gxb == W - 4) xR = -BIGF;
        dil->x = max3f(xL,   xm.x, xm.y);
        dil->y = max3f(xm.x, xm.y, xm.z);
        dil->z = max3f(xm.y, xm.z, xm.w);
        dil->w = max3f(xm.z, xm.w, xR);
    }
    return o;
}

// standalone masked dilate (final delta only)
__device__ __forceinline__ float4 dil_grp(const float* __restrict__ e,
    int lr, int c, int gy, int gxb, bool fL, bool fR)
{
    const float* s1 = e + lr * SC + c;
    float4 a = ld4(s1 - SC), b = ld4(s1), cc = ld4(s1 + SC);
    const bool t = (gy > 0), u = (gy < H - 1);
    float4 xm;
    xm.x = fmaxf(b.x, fmaxf(t ? a.x : -BIGF, u ? cc.x : -BIGF));
    xm.y = fmaxf(b.y, fmaxf(t ? a.y : -BIGF, u ? cc.y : -BIGF));
    xm.z = fmaxf(b.z, fmaxf(t ? a.z : -BIGF, u ? cc.z : -BIGF));
    xm.w = fmaxf(b.w, fmaxf(t ? a.w : -BIGF, u ? cc.w : -BIGF));
    float xL = __shfl_up(xm.w, 1);
    float xR = __shfl_down(xm.x, 1);
    if (fL) xL = max3f(t ? s1[-SC - 1] : -BIGF, s1[-1], u ? s1[SC - 1] : -BIGF);
    if (fR) xR = max3f(t ? s1[-SC + 4] : -BIGF, s1[4],  u ? s1[SC + 4] : -BIGF);
    if (gxb == 0)     xL = -BIGF;
    if (gxb == W - 4) xR = -BIGF;
    float4 d;
    d.x = max3f(xL,   xm.x, xm.y);
    d.y = max3f(xm.x, xm.y, xm.z);
    d.z = max3f(xm.y, xm.z, xm.w);
    d.w = max3f(xm.z, xm.w, xR);
    return d;
}

__device__ __forceinline__ void skupd(float4& sk, const float4& cur, const float4& d)
{
    float4 del;
    del.x = fmaxf(cur.x - d.x, 0.f);
    del.y = fmaxf(cur.y - d.y, 0.f);
    del.z = fmaxf(cur.z - d.z, 0.f);
    del.w = fmaxf(cur.w - d.w, 0.f);
    sk.x += fmaxf(del.x - sk.x * del.x, 0.f);
    sk.y += fmaxf(del.y - sk.y * del.y, 0.f);
    sk.z += fmaxf(del.z - sk.z * del.z, 0.f);
    sk.w += fmaxf(del.w - sk.w * del.w, 0.f);
}

// ---------------------------------------------------------------------------
// fused skeleton, 13 erode passes / launch, sk + cur in registers,
// 1 sync/iter, dilate fused into the erode pass (shared b128 loads).
// Fixed thread->group mapping: 2 output groups (rows 14..77, g 4..19) +
// 1 extra central group (g in {0..3,20..23}) + strided halo rows.
// MODE 0: first launch (delta0..delta12; writes im_out=e^12 and gsk)
// MODE 2: last  launch (delta13..delta24; fused reduction, no writes)
// ---------------------------------------------------------------------------
template<int MODE>
__global__ __launch_bounds__(NT, 4) void skel_kernel(
    const float* __restrict__ in, float* __restrict__ im_out,
    float* __restrict__ gsk, const float* __restrict__ prob,
    double* __restrict__ sums)
{
    __shared__ __align__(16) float lds[2 * SR * SC + 32];
    float* const bx = lds + 16;          // front guard 16 floats
    float* const by = bx + SR * SC;
    const int pl  = blockIdx.z;
    const int ty0 = blockIdx.y * 64, tx0 = blockIdx.x * 64;
    const int tid = threadIdx.x, lane = tid & 63;
    const float* ip = in + (size_t)pl * P;
    const size_t gbase = (size_t)pl * P;

    // output groups: (lrA, g=4+j) and (lrB, g=4+j); lanes 0..15 are
    // horizontally adjacent -> shfl edges, fallback only at j==0/15.
    const int j   = tid & 15;
    const int py  = tid >> 4;
    const int cA  = 16 + 4 * j;
    const int lrA = 14 + py, lrB = 46 + py;
    const int gyA = ty0 + py, gyB = gyA + 32;
    const int gxb = tx0 + 4 * j;
    const bool fL = (j == 0), fR = (j == 15);

    // extra central group: row 14+(tid>>3), g in {0,1,2,3,20,21,22,23}
    const int e8 = tid & 7;
    const int rX = 14 + (tid >> 3);
    const int gX = (e8 < 4) ? e8 : 16 + e8;
    const int cX = 4 * gX;
    const bool xfL = (e8 == 0) || (e8 == 4);
    const bool xfR = (e8 == 3) || (e8 == 7);

    // ---- stage e^0 into bx (replicate clamp; exact for erosion chains) ----
    const bool xin = (tx0 >= 16) && (tx0 <= W - 80);
    for (int idx = tid; idx < SR * 24; idx += NT) {
        int r = idx / 24, g = idx % 24;
        int gy = ty0 - HR + r; gy = min(max(gy, 0), H - 1);
        int gx0 = tx0 - 16 + 4 * g;
        float4 v;
        if (xin) {
            v = ld4(ip + (size_t)gy * W + gx0);
        } else {
            const float* rp = ip + (size_t)gy * W;
            v.x = rp[min(max(gx0,     0), W - 1)];
            v.y = rp[min(max(gx0 + 1, 0), W - 1)];
            v.z = rp[min(max(gx0 + 2, 0), W - 1)];
            v.w = rp[min(max(gx0 + 3, 0), W - 1)];
        }
        *reinterpret_cast<float4*>(&bx[r * SC + 4 * g]) = v;
    }

    float4 sk0, sk1;
    if (MODE == 0) {
        sk0 = make_float4(0.f, 0.f, 0.f, 0.f);
        sk1 = sk0;
    } else {
        sk0 = ld4(gsk + gbase + (size_t)gyA * W + gxb);
        sk1 = ld4(gsk + gbase + (size_t)gyB * W + gxb);
    }
    __syncthreads();

    // ---- phase 1: erode e^0 -> by ; capture e^0 centers (free) ----
    float4 curA, curB, dump;
    {
        float4 oA = fused_grp<false>(bx, lrA, cA, gyA, gxb, fL, fR, &curA, &dump);
        *reinterpret_cast<float4*>(by + lrA * SC + cA) = oA;
        float4 oB = fused_grp<false>(bx, lrB, cA, gyB, gxb, fL, fR, &curB, &dump);
        *reinterpret_cast<float4*>(by + lrB * SC + cA) = oB;
        float4 oX = erode_grp(bx, rX, cX, xfL, xfR);
        *reinterpret_cast<float4*>(by + rX * SC + cX) = oX;
        const int nb = HR - 1;                        // 13 halo rows per side
        for (int idx = tid; idx < 2 * nb * 24; idx += NT) {
            int rb = idx / 24, g = idx % 24;
            int r = (rb < nb) ? 1 + rb : 78 + (rb - nb);
            bool hfL = (g == 0) || (lane == 0), hfR = (g == 23) || (lane == 63);
            float4 o = erode_grp(bx, r, 4 * g, hfL, hfR);
            *reinterpret_cast<float4*>(by + r * SC + 4 * g) = o;
        }
    }
    __syncthreads();

    // ---- phases p=2..13: fused {erode_p + dilate(e^{p-1}) + delta_{p-2}} ----
    for (int p = 2; p <= E; ++p) {
        const float* src = (p & 1) ? bx : by;        // holds e^{p-1}
        float*       dst = (p & 1) ? by : bx;
        float4 nA, nB, dA, dB;
        float4 oA = fused_grp<true>(src, lrA, cA, gyA, gxb, fL, fR, &nA, &dA);
        *reinterpret_cast<float4*>(dst + lrA * SC + cA) = oA;
        if (MODE == 0 || p > 2) skupd(sk0, curA, dA);
        curA = nA;
        float4 oB = fused_grp<true>(src, lrB, cA, gyB, gxb, fL, fR, &nB, &dB);
        *reinterpret_cast<float4*>(dst + lrB * SC + cA) = oB;
        if (MODE == 0 || p > 2) skupd(sk1, curB, dB);
        curB = nB;
        float4 oX = erode_grp(src, rX, cX, xfL, xfR);
        *reinterpret_cast<float4*>(dst + rX * SC + cX) = oX;
        const int nb = HR - p;
        for (int idx = tid; idx < 2 * nb * 24; idx += NT) {
            int rb = idx / 24, g = idx % 24;
            int r = (rb < nb) ? p + rb : 78 + (rb - nb);
            bool hfL = (g == 0) || (lane == 0), hfR = (g == 23) || (lane == 63);
            float4 o = erode_grp(src, r, 4 * g, hfL, hfR);
            *reinterpret_cast<float4*>(dst + r * SC + 4 * g) = o;
        }
        __syncthreads();
    }

    // ---- final delta_12(local): cur = e^12, dilate(e^13 in by) ----
    {
        float4 dA = dil_grp(by, lrA, cA, gyA, gxb, fL, fR);
        float4 dB = dil_grp(by, lrB, cA, gyB, gxb, fL, fR);
        skupd(sk0, curA, dA);
        skupd(sk1, curB, dB);
    }

    if (MODE == 0) {
        *reinterpret_cast<float4*>(im_out + gbase + (size_t)gyA * W + gxb) = curA;
        *reinterpret_cast<float4*>(im_out + gbase + (size_t)gyB * W + gxb) = curB;
        *reinterpret_cast<float4*>(gsk + gbase + (size_t)gyA * W + gxb) = sk0;
        *reinterpret_cast<float4*>(gsk + gbase + (size_t)gyB * W + gxb) = sk1;
    } else {
        // fused reduction: student plane -> sums[b][0,1]; teacher -> [2,3]
        const float* op = prob + (size_t)(pl ^ 8) * P;
        float4 tA = ld4(op + (size_t)gyA * W + gxb);
        float4 tB = ld4(op + (size_t)gyB * W + gxb);
        float a0 = sk0.x * tA.x + sk0.y * tA.y + sk0.z * tA.z + sk0.w * tA.w
                 + sk1.x * tB.x + sk1.y * tB.y + sk1.z * tB.z + sk1.w * tB.w;
        float a1 = sk0.x + sk0.y + sk0.z + sk0.w + sk1.x + sk1.y + sk1.z + sk1.w;
        #pragma unroll
        for (int off = 32; off > 0; off >>= 1) {
            a0 += __shfl_down(a0, off);
            a1 += __shfl_down(a1, off);
        }
        __syncthreads();
        float* scratch = lds;
        int wv = tid >> 6, ln = tid & 63;
        if (ln == 0) { scratch[wv * 2] = a0; scratch[wv * 2 + 1] = a1; }
        __syncthreads();
        if (tid == 0) {
            double s0 = 0.0, s1 = 0.0;
            for (int w = 0; w < NT / 64; ++w) {
                s0 += (double)scratch[w * 2];
                s1 += (double)scratch[w * 2 + 1];
            }
            int b = pl & 7, base = (pl < 8) ? 0 : 2;
            atomicAdd(&sums[b * 4 + base + 0], s0);
            atomicAdd(&sums[b * 4 + base + 1], s1);
        }
    }
}

__global__ void final_kernel(const double* __restrict__ sums, float* __restrict__ out)
{
    if (threadIdx.x == 0) {
        double acc = 0.0;
        for (int b = 0; b < 8; ++b) {
            double tprec = (sums[b * 4 + 0] + 1e-6) / (sums[b * 4 + 1] + 1e-6);
            double tsens = (sums[b * 4 + 2] + 1e-6) / (sums[b * 4 + 3] + 1e-6);
            double cl    = (2.0 * tprec * tsens + 1e-6) / (tprec + tsens + 1e-6);
            acc += 1.0 - cl;
        }
        out[0] = (float)(acc / 8.0);
    }
}

extern "C" void kernel_launch(void* const* d_in, const int* in_sizes, int n_in,
                              void* d_out, int out_size, void* d_ws, size_t ws_size,
                              hipStream_t stream)
{
    const float* logits = (const float*)d_in[0];
    const float* mask   = (const float*)d_in[1];
    const int*   cls    = (const int*)d_in[2];
    float* out = (float*)d_out;

    float*  ws   = (float*)d_ws;
    float*  prob = ws;                          // 16 planes (pristine)
    float*  imA  = ws + (size_t)16 * P;         // e^12 handoff
    float*  gsk  = ws + (size_t)32 * P;         // skeleton accumulator
    double* sums = (double*)(ws + (size_t)48 * P);   // 32 doubles

    dim3 sg(8, 8, NPL);
    prep_kernel<<<(B * (P / 4) + 255) / 256, 256, 0, stream>>>(logits, mask, cls, prob, sums);
    skel_kernel<0><<<sg, NT, 0, stream>>>(prob, imA, gsk, prob, sums);    // d0..d12
    skel_kernel<2><<<sg, NT, 0, stream>>>(imA, nullptr, gsk, prob, sums); // d13..d24 + reduce
    final_kernel<<<1, 64, 0, stream>>>(sums, out);
}

// Round 7
// 349.193 us; speedup vs baseline: 2.5290x; 1.0423x over previous
//
#include <hip/hip_runtime.h>

#define B 8
#define C 19
#define H 512
#define W 512
#define P (H*W)          // pixels per plane
#define NPL 16           // 8 student + 8 teacher planes
#define BIGF 1e30f
#define NT 512           // threads per skel block
#define HR 16            // staged row halo (>= E+1; 16 for 4-row strip align)
#define SC 96            // staged cols (tx0-16 .. tx0+79)
#define LROWS 98         // 96 staged rows + 2 guard rows
#define E  13            // erode passes per launch

__device__ __forceinline__ float min3f(float a, float b, float c) { return fminf(fminf(a, b), c); }
__device__ __forceinline__ float max3f(float a, float b, float c) { return fmaxf(fmaxf(a, b), c); }
__device__ __forceinline__ float4 ld4(const float* p) { return *reinterpret_cast<const float4*>(p); }

// ---------------------------------------------------------------------------
// prep: student softmax prob for class ci + teacher clip; zeros sums.
// ---------------------------------------------------------------------------
__global__ __launch_bounds__(256) void prep_kernel(
    const float* __restrict__ logits, const float* __restrict__ mask,
    const int* __restrict__ cls, float* __restrict__ prob,
    double* __restrict__ sums)
{
    if (blockIdx.x == 0 && threadIdx.x < 32) sums[threadIdx.x] = 0.0;
    int tid = blockIdx.x * 256 + threadIdx.x;
    const int tot = B * (P / 4);
    if (tid >= tot) return;
    int b  = tid / (P / 4);
    int i4 = tid % (P / 4);
    int ci = *cls;

    const float4* lg = reinterpret_cast<const float4*>(logits) + (size_t)b * C * (P / 4) + i4;
    float4 v[C];
    float4 vc = make_float4(0.f, 0.f, 0.f, 0.f);
    #pragma unroll
    for (int c = 0; c < C; ++c) {
        float4 t = lg[(size_t)c * (P / 4)];
        v[c] = t;
        if (c == ci) vc = t;
    }
    float4 mx = v[0];
    #pragma unroll
    for (int c = 1; c < C; ++c) {
        mx.x = fmaxf(mx.x, v[c].x); mx.y = fmaxf(mx.y, v[c].y);
        mx.z = fmaxf(mx.z, v[c].z); mx.w = fmaxf(mx.w, v[c].w);
    }
    float4 s = make_float4(0.f, 0.f, 0.f, 0.f);
    #pragma unroll
    for (int c = 0; c < C; ++c) {
        s.x += expf(v[c].x - mx.x); s.y += expf(v[c].y - mx.y);
        s.z += expf(v[c].z - mx.z); s.w += expf(v[c].w - mx.w);
    }
    float4 p;
    p.x = expf(vc.x - mx.x) / s.x;
    p.y = expf(vc.y - mx.y) / s.y;
    p.z = expf(vc.z - mx.z) / s.z;
    p.w = expf(vc.w - mx.w) / s.w;

    float4* pr = reinterpret_cast<float4*>(prob);
    pr[(size_t)b * (P / 4) + i4] = p;

    float4 tm = reinterpret_cast<const float4*>(mask)[(size_t)b * (P / 4) + i4];
    tm.x = fminf(fmaxf(tm.x, 0.f), 1.f);
    tm.y = fminf(fmaxf(tm.y, 0.f), 1.f);
    tm.z = fminf(fmaxf(tm.z, 0.f), 1.f);
    tm.w = fminf(fmaxf(tm.w, 0.f), 1.f);
    pr[(size_t)(8 + b) * (P / 4) + i4] = tm;
}

// ---------------------------------------------------------------------------
// peripheral strip: erode 4 rows (staged 4s..4s+3) from 6 shared b128 reads.
// off = 4s*SC + 4g (read base = buffer row 4s = staged row 4s-1).
// ---------------------------------------------------------------------------
__device__ __forceinline__ void strip_erode(const float* __restrict__ src,
    float* __restrict__ dst, int off, bool fL, bool fR)
{
    const float* sp = src + off;
    float* dp = dst + off;
    float4 rr[6];
    #pragma unroll
    for (int k = 0; k < 6; ++k) rr[k] = ld4(sp + k * SC);
    float4 vm[4];
    #pragma unroll
    for (int k = 0; k < 4; ++k) {
        vm[k].x = min3f(rr[k].x, rr[k+1].x, rr[k+2].x);
        vm[k].y = min3f(rr[k].y, rr[k+1].y, rr[k+2].y);
        vm[k].z = min3f(rr[k].z, rr[k+1].z, rr[k+2].z);
        vm[k].w = min3f(rr[k].w, rr[k+1].w, rr[k+2].w);
    }
    float vls[4], vrs[4];
    #pragma unroll
    for (int k = 0; k < 4; ++k) {
        vls[k] = __shfl_up(vm[k].w, 1);
        vrs[k] = __shfl_down(vm[k].x, 1);
    }
    if (fL) {
        float e0 = sp[-1], e1 = sp[SC-1], e2 = sp[2*SC-1],
              e3 = sp[3*SC-1], e4 = sp[4*SC-1], e5 = sp[5*SC-1];
        vls[0] = min3f(e0, e1, e2); vls[1] = min3f(e1, e2, e3);
        vls[2] = min3f(e2, e3, e4); vls[3] = min3f(e3, e4, e5);
    }
    if (fR) {
        float e0 = sp[4], e1 = sp[SC+4], e2 = sp[2*SC+4],
              e3 = sp[3*SC+4], e4 = sp[4*SC+4], e5 = sp[5*SC+4];
        vrs[0] = min3f(e0, e1, e2); vrs[1] = min3f(e1, e2, e3);
        vrs[2] = min3f(e2, e3, e4); vrs[3] = min3f(e3, e4, e5);
    }
    #pragma unroll
    for (int k = 0; k < 4; ++k) {
        float4 o;
        o.x = min3f(vls[k],  vm[k].x, vm[k].y);
        o.y = min3f(vm[k].x, vm[k].y, vm[k].z);
        o.z = min3f(vm[k].y, vm[k].z, vm[k].w);
        o.w = min3f(vm[k].z, vm[k].w, vrs[k]);
        *reinterpret_cast<float4*>(dp + (k + 1) * SC) = o;
    }
}

__device__ __forceinline__ void skupd(float4& sk, const float4& cur, const float4& d)
{
    float4 del;
    del.x = fmaxf(cur.x - d.x, 0.f);
    del.y = fmaxf(cur.y - d.y, 0.f);
    del.z = fmaxf(cur.z - d.z, 0.f);
    del.w = fmaxf(cur.w - d.w, 0.f);
    sk.x += fmaxf(del.x - sk.x * del.x, 0.f);
    sk.y += fmaxf(del.y - sk.y * del.y, 0.f);
    sk.z += fmaxf(del.z - sk.z * del.z, 0.f);
    sk.w += fmaxf(del.w - sk.w * del.w, 0.f);
}

// ---------------------------------------------------------------------------
// central strip: erode (+ masked dilate of src + skupd when DIL) + capture cur
// from the SAME 6 b128 reads. Output rows gy0..gy0+3, cols gxb..gxb+3.
// ---------------------------------------------------------------------------
template<bool DIL>
__device__ __forceinline__ void central_strip(const float* __restrict__ src,
    float* __restrict__ dst, int off, bool fL, bool fR, int gy0, int gxb,
    float4* __restrict__ cur, float4* __restrict__ sk, bool dosk)
{
    const float* sp = src + off;
    float* dp = dst + off;
    float4 rr[6];
    #pragma unroll
    for (int k = 0; k < 6; ++k) rr[k] = ld4(sp + k * SC);
    float eL[6], eR[6];
    if (fL) {
        #pragma unroll
        for (int k = 0; k < 6; ++k) eL[k] = sp[k * SC - 1];
    }
    if (fR) {
        #pragma unroll
        for (int k = 0; k < 6; ++k) eR[k] = sp[k * SC + 4];
    }
    // erode
    {
        float4 vm[4];
        #pragma unroll
        for (int k = 0; k < 4; ++k) {
            vm[k].x = min3f(rr[k].x, rr[k+1].x, rr[k+2].x);
            vm[k].y = min3f(rr[k].y, rr[k+1].y, rr[k+2].y);
            vm[k].z = min3f(rr[k].z, rr[k+1].z, rr[k+2].z);
            vm[k].w = min3f(rr[k].w, rr[k+1].w, rr[k+2].w);
        }
        float vls[4], vrs[4];
        #pragma unroll
        for (int k = 0; k < 4; ++k) {
            vls[k] = __shfl_up(vm[k].w, 1);
            vrs[k] = __shfl_down(vm[k].x, 1);
        }
        if (fL) {
            #pragma unroll
            for (int k = 0; k < 4; ++k) vls[k] = min3f(eL[k], eL[k+1], eL[k+2]);
        }
        if (fR) {
            #pragma unroll
            for (int k = 0; k < 4; ++k) vrs[k] = min3f(eR[k], eR[k+1], eR[k+2]);
        }
        #pragma unroll
        for (int k = 0; k < 4; ++k) {
            float4 o;
            o.x = min3f(vls[k],  vm[k].x, vm[k].y);
            o.y = min3f(vm[k].x, vm[k].y, vm[k].z);
            o.z = min3f(vm[k].y, vm[k].z, vm[k].w);
            o.w = min3f(vm[k].z, vm[k].w, vrs[k]);
            *reinterpret_cast<float4*>(dp + (k + 1) * SC) = o;
        }
    }
    if (DIL) {
        float4 xm[4];
        #pragma unroll
        for (int k = 0; k < 4; ++k) {
            const bool t = (gy0 + k) > 0, u = (gy0 + k) < H - 1;
            xm[k].x = fmaxf(rr[k+1].x, fmaxf(t ? rr[k].x : -BIGF, u ? rr[k+2].x : -BIGF));
            xm[k].y = fmaxf(rr[k+1].y, fmaxf(t ? rr[k].y : -BIGF, u ? rr[k+2].y : -BIGF));
            xm[k].z = fmaxf(rr[k+1].z, fmaxf(t ? rr[k].z : -BIGF, u ? rr[k+2].z : -BIGF));
            xm[k].w = fmaxf(rr[k+1].w, fmaxf(t ? rr[k].w : -BIGF, u ? rr[k+2].w : -BIGF));
        }
        float xls[4], xrs[4];
        #pragma unroll
        for (int k = 0; k < 4; ++k) {
            xls[k] = __shfl_up(xm[k].w, 1);
            xrs[k] = __shfl_down(xm[k].x, 1);
        }
        if (fL) {
            #pragma unroll
            for (int k = 0; k < 4; ++k) {
                const bool t = (gy0 + k) > 0, u = (gy0 + k) < H - 1;
                xls[k] = max3f(t ? eL[k] : -BIGF, eL[k+1], u ? eL[k+2] : -BIGF);
            }
        }
        if (fR) {
            #pragma unroll
            for (int k = 0; k < 4; ++k) {
                const bool t = (gy0 + k) > 0, u = (gy0 + k) < H - 1;
                xrs[k] = max3f(t ? eR[k] : -BIGF, eR[k+1], u ? eR[k+2] : -BIGF);
            }
        }
        if (gxb == 0) {
            #pragma unroll
            for (int k = 0; k < 4; ++k) xls[k] = -BIGF;
        }
        if (gxb == W - 4) {
            #pragma unroll
            for (int k = 0; k < 4; ++k) xrs[k] = -BIGF;
        }
        if (dosk) {
            #pragma unroll
            for (int k = 0; k < 4; ++k) {
                float4 d;
                d.x = max3f(xls[k],  xm[k].x, xm[k].y);
                d.y = max3f(xm[k].x, xm[k].y, xm[k].z);
                d.z = max3f(xm[k].y, xm[k].z, xm[k].w);
                d.w = max3f(xm[k].z, xm[k].w, xrs[k]);
                skupd(sk[k], cur[k], d);
            }
        }
    }
    #pragma unroll
    for (int k = 0; k < 4; ++k) cur[k] = rr[k + 1];
}

// final dilate-only (e^E in src) + skupd
__device__ __forceinline__ void central_fdil(const float* __restrict__ src,
    int off, bool fL, bool fR, int gy0, int gxb,
    const float4* __restrict__ cur, float4* __restrict__ sk)
{
    const float* sp = src + off;
    float4 rr[6];
    #pragma unroll
    for (int k = 0; k < 6; ++k) rr[k] = ld4(sp + k * SC);
    float eL[6], eR[6];
    if (fL) {
        #pragma unroll
        for (int k = 0; k < 6; ++k) eL[k] = sp[k * SC - 1];
    }
    if (fR) {
        #pragma unroll
        for (int k = 0; k < 6; ++k) eR[k] = sp[k * SC + 4];
    }
    float4 xm[4];
    #pragma unroll
    for (int k = 0; k < 4; ++k) {
        const bool t = (gy0 + k) > 0, u = (gy0 + k) < H - 1;
        xm[k].x = fmaxf(rr[k+1].x, fmaxf(t ? rr[k].x : -BIGF, u ? rr[k+2].x : -BIGF));
        xm[k].y = fmaxf(rr[k+1].y, fmaxf(t ? rr[k].y : -BIGF, u ? rr[k+2].y : -BIGF));
        xm[k].z = fmaxf(rr[k+1].z, fmaxf(t ? rr[k].z : -BIGF, u ? rr[k+2].z : -BIGF));
        xm[k].w = fmaxf(rr[k+1].w, fmaxf(t ? rr[k].w : -BIGF, u ? rr[k+2].w : -BIGF));
    }
    float xls[4], xrs[4];
    #pragma unroll
    for (int k = 0; k < 4; ++k) {
        xls[k] = __shfl_up(xm[k].w, 1);
        xrs[k] = __shfl_down(xm[k].x, 1);
    }
    if (fL) {
        #pragma unroll
        for (int k = 0; k < 4; ++k) {
            const bool t = (gy0 + k) > 0, u = (gy0 + k) < H - 1;
            xls[k] = max3f(t ? eL[k] : -BIGF, eL[k+1], u ? eL[k+2] : -BIGF);
        }
    }
    if (fR) {
        #pragma unroll
        for (int k = 0; k < 4; ++k) {
            const bool t = (gy0 + k) > 0, u = (gy0 + k) < H - 1;
            xrs[k] = max3f(t ? eR[k] : -BIGF, eR[k+1], u ? eR[k+2] : -BIGF);
        }
    }
    if (gxb == 0) {
        #pragma unroll
        for (int k = 0; k < 4; ++k) xls[k] = -BIGF;
    }
    if (gxb == W - 4) {
        #pragma unroll
        for (int k = 0; k < 4; ++k) xrs[k] = -BIGF;
    }
    #pragma unroll
    for (int k = 0; k < 4; ++k) {
        float4 d;
        d.x = max3f(xls[k],  xm[k].x, xm[k].y);
        d.y = max3f(xm[k].x, xm[k].y, xm[k].z);
        d.z = max3f(xm[k].y, xm[k].z, xm[k].w);
        d.w = max3f(xm[k].z, xm[k].w, xrs[k]);
        skupd(sk[k], cur[k], d);
    }
}

// peripheral strip list decode: 320 strips = all (s,g) in 24x24 minus the
// 16x16 central block (s,g in 4..19).
__device__ __forceinline__ void pdecode(int idx, int& s, int& g)
{
    if (idx < 96)       { s = idx / 24;      g = idx - s * 24; }
    else if (idx < 224) { int k = idx - 96;  s = 4 + (k >> 3); int t = k & 7; g = (t < 4) ? t : 16 + t; }
    else                { int k = idx - 224; int q = k / 24;   s = 20 + q;    g = k - q * 24; }
}

// ---------------------------------------------------------------------------
// fused skeleton: 13 erode passes / launch; thread = one 4-row strip.
// Waves 0-3: 256 central strips (erode+dilate+delta, sk/cur in regs).
// Waves 4-7: 320 peripheral strips (erode only; wave 4 takes the extra 64).
// MODE 0: delta0..delta12, writes im_out=e^12 + gsk.
// MODE 2: delta13..delta24 + fused reduction.
// ---------------------------------------------------------------------------
template<int MODE>
__global__ __launch_bounds__(NT, 4) void skel_kernel(
    const float* __restrict__ in, float* __restrict__ im_out,
    float* __restrict__ gsk, const float* __restrict__ prob,
    double* __restrict__ sums)
{
    __shared__ __align__(16) float lds[16 + 2 * LROWS * SC + 16];
    float* const bx = lds + 16;
    float* const by = bx + LROWS * SC;
    const int pl  = blockIdx.z;
    const int ty0 = blockIdx.y * 64, tx0 = blockIdx.x * 64;
    const int tid = threadIdx.x, lane = tid & 63;
    const float* ip = in + (size_t)pl * P;
    const size_t gbase = (size_t)pl * P;

    const bool is_c = (tid < 256);
    const int sr = (tid >> 4) & 15;
    const int sc = tid & 15;
    const int r0 = 16 + 4 * sr;                      // staged first output row
    const int coff = r0 * SC + 16 + 4 * sc;          // read base (buffer row r0)
    const int gy0 = ty0 + 4 * sr;
    const int gxb = tx0 + 4 * sc;
    const bool cfL = (sc == 0), cfR = (sc == 15);

    int  p1off = 0, p2off = 0;
    bool p1L = false, p1R = false, p2L = false, p2R = false, has2 = false;
    if (!is_c) {
        int i1 = tid - 256, s, g;
        pdecode(i1, s, g);
        bool mid = (s >= 4 && s <= 19);
        p1L = (g == 0)  || (lane == 0)  || (mid && g == 20);
        p1R = (g == 23) || (lane == 63) || (mid && g == 3);
        p1off = 4 * s * SC + 4 * g;
        has2 = (i1 < 64);                            // wave 4 only (uniform)
        if (has2) {
            pdecode(256 + i1, s, g);
            mid = (s >= 4 && s <= 19);
            p2L = (g == 0)  || (lane == 0)  || (mid && g == 20);
            p2R = (g == 23) || (lane == 63) || (mid && g == 3);
            p2off = 4 * s * SC + 4 * g;
        }
    }

    // ---- stage e^0 into bx rows 1..96 (replicate clamp; exact for erosion) --
    const bool xin = (tx0 >= 16) && (tx0 <= W - 80);
    for (int idx = tid; idx < 96 * 24; idx += NT) {
        int r = idx / 24, g = idx - (idx / 24) * 24;
        int gy = min(max(ty0 - HR + r, 0), H - 1);
        int gx0 = tx0 - 16 + 4 * g;
        float4 v;
        if (xin) {
            v = ld4(ip + (size_t)gy * W + gx0);
        } else {
            const float* rp = ip + (size_t)gy * W;
            v.x = rp[min(max(gx0,     0), W - 1)];
            v.y = rp[min(max(gx0 + 1, 0), W - 1)];
            v.z = rp[min(max(gx0 + 2, 0), W - 1)];
            v.w = rp[min(max(gx0 + 3, 0), W - 1)];
        }
        *reinterpret_cast<float4*>(&bx[(r + 1) * SC + 4 * g]) = v;
    }

    float4 sk[4], cur[4];
    if (is_c) {
        if (MODE == 0) {
            #pragma unroll
            for (int k = 0; k < 4; ++k) sk[k] = make_float4(0.f, 0.f, 0.f, 0.f);
        } else {
            #pragma unroll
            for (int k = 0; k < 4; ++k)
                sk[k] = ld4(gsk + gbase + (size_t)(gy0 + k) * W + gxb);
        }
    }
    __syncthreads();

    // ---- phase 1: erode e^0 -> by ; central captures cur = e^0 ----
    if (is_c) {
        central_strip<false>(bx, by, coff, cfL, cfR, gy0, gxb, cur, sk, false);
    } else {
        strip_erode(bx, by, p1off, p1L, p1R);
        if (has2) strip_erode(bx, by, p2off, p2L, p2R);
    }
    __syncthreads();

    // ---- phases p=2..13: erode_p + dilate(e^{p-1}) + delta_{p-2} ----
    for (int p = 2; p <= E; ++p) {
        const float* src = (p & 1) ? bx : by;        // holds e^{p-1}
        float*       dst = (p & 1) ? by : bx;
        const bool dosk = (MODE == 0) || (p > 2);
        if (is_c) {
            central_strip<true>(src, dst, coff, cfL, cfR, gy0, gxb, cur, sk, dosk);
        } else {
            strip_erode(src, dst, p1off, p1L, p1R);
            if (has2) strip_erode(src, dst, p2off, p2L, p2R);
        }
        __syncthreads();
    }

    // ---- final delta: cur = e^12, dilate(e^13 in by) ----
    if (is_c) central_fdil(by, coff, cfL, cfR, gy0, gxb, cur, sk);

    if (MODE == 0) {
        if (is_c) {
            #pragma unroll
            for (int k = 0; k < 4; ++k) {
                size_t gi = gbase + (size_t)(gy0 + k) * W + gxb;
                *reinterpret_cast<float4*>(im_out + gi) = cur[k];
                *reinterpret_cast<float4*>(gsk + gi)    = sk[k];
            }
        }
    } else {
        float a0 = 0.f, a1 = 0.f;
        if (is_c) {
            const float* op = prob + (size_t)(pl ^ 8) * P;
            #pragma unroll
            for (int k = 0; k < 4; ++k) {
                float4 t4 = ld4(op + (size_t)(gy0 + k) * W + gxb);
                a0 += sk[k].x * t4.x + sk[k].y * t4.y + sk[k].z * t4.z + sk[k].w * t4.w;
                a1 += sk[k].x + sk[k].y + sk[k].z + sk[k].w;
            }
        }
        #pragma unroll
        for (int off = 32; off > 0; off >>= 1) {
            a0 += __shfl_down(a0, off);
            a1 += __shfl_down(a1, off);
        }
        if (is_c && lane == 0) {
            lds[(tid >> 6) * 2]     = a0;
            lds[(tid >> 6) * 2 + 1] = a1;
        }
        __syncthreads();
        if (tid == 0) {
            double s0 = 0.0, s1 = 0.0;
            #pragma unroll
            for (int w = 0; w < 4; ++w) {
                s0 += (double)lds[w * 2];
                s1 += (double)lds[w * 2 + 1];
            }
            int b = pl & 7, base = (pl < 8) ? 0 : 2;
            atomicAdd(&sums[b * 4 + base + 0], s0);
            atomicAdd(&sums[b * 4 + base + 1], s1);
        }
    }
}

__global__ void final_kernel(const double* __restrict__ sums, float* __restrict__ out)
{
    if (threadIdx.x == 0) {
        double acc = 0.0;
        for (int b = 0; b < 8; ++b) {
            double tprec = (sums[b * 4 + 0] + 1e-6) / (sums[b * 4 + 1] + 1e-6);
            double tsens = (sums[b * 4 + 2] + 1e-6) / (sums[b * 4 + 3] + 1e-6);
            double cl    = (2.0 * tprec * tsens + 1e-6) / (tprec + tsens + 1e-6);
            acc += 1.0 - cl;
        }
        out[0] = (float)(acc / 8.0);
    }
}

extern "C" void kernel_launch(void* const* d_in, const int* in_sizes, int n_in,
                              void* d_out, int out_size, void* d_ws, size_t ws_size,
                              hipStream_t stream)
{
    const float* logits = (const float*)d_in[0];
    const float* mask   = (const float*)d_in[1];
    const int*   cls    = (const int*)d_in[2];
    float* out = (float*)d_out;

    float*  ws   = (float*)d_ws;
    float*  prob = ws;                          // 16 planes (pristine)
    float*  imA  = ws + (size_t)16 * P;         // e^12 handoff
    float*  gsk  = ws + (size_t)32 * P;         // skeleton accumulator
    double* sums = (double*)(ws + (size_t)48 * P);   // 32 doubles

    dim3 sg(8, 8, NPL);
    prep_kernel<<<(B * (P / 4) + 255) / 256, 256, 0, stream>>>(logits, mask, cls, prob, sums);
    skel_kernel<0><<<sg, NT, 0, stream>>>(prob, imA, gsk, prob, sums);    // d0..d12
    skel_kernel<2><<<sg, NT, 0, stream>>>(imA, nullptr, gsk, prob, sums); // d13..d24 + reduce
    final_kernel<<<1, 64, 0, stream>>>(sums, out);
}